// Round 3
// baseline (146.533 us; speedup 1.0000x reference)
//
#include <hip/hip_runtime.h>
#include <hip/hip_bf16.h>

typedef __attribute__((ext_vector_type(8))) short short8;
typedef __attribute__((ext_vector_type(4))) float f32x4;

#define BM 64
#define BN 128
#define BK 64
#define THREADS 512
#define IN_F 512
#define OUT_F 512
#define PHI_STEPS 64
#define NSTEPS 72
#define NT (OUT_F / BN)          // 4 n-tiles
#define IMG_SHORTS (BN * BK)     // one 16 KB pre-swizzled B image per (nt, step)

__device__ __forceinline__ short f2bf(float f) {
  __hip_bfloat16 h = __float2bfloat16(f);
  return __builtin_bit_cast(short, h);
}

__device__ __forceinline__ void glds16(const void* g, void* l) {
  // 16-byte global -> LDS direct copy; LDS dest wave-uniform base (+lane*16).
  __builtin_amdgcn_global_load_lds(
      (const __attribute__((address_space(1))) unsigned int*)g,
      (__attribute__((address_space(3))) unsigned int*)l, 16, 0, 0);
}

__device__ __forceinline__ float bsrc(const float* __restrict__ w,
                                      const float* __restrict__ sb,
                                      int k, int col) {
  return (k < IN_F * 8) ? w[(size_t)k * OUT_F + col]
                        : sb[(size_t)(k - IN_F * 8) * OUT_F + col];
}

// Pre-convert B = [w ; scale_base] (K=4608 x N=512, f32) into bf16 images laid
// out EXACTLY as the main kernel's LDS B-tile bytes (swizzle slot = oct^(n&7)),
// one image per (n_tile, k_step). Coalesced 16B writes.
__global__ void __launch_bounds__(512) prep_b(const float* __restrict__ w,
                                              const float* __restrict__ sb,
                                              short* __restrict__ img) {
  const int d = blockIdx.x * 512 + threadIdx.x;    // 16B-chunk id
  const int slot = d & 7;
  const int n = (d >> 3) & (BN - 1);
  const int s = (d >> 10) % NSTEPS;
  const int nt = d / (NSTEPS * 1024);
  const int oct = slot ^ (n & 7);
  const int col = nt * BN + n;
  short8 v;
#pragma unroll
  for (int j = 0; j < 8; ++j) {
    const int k = s * 64 + oct * 8 + j;
    v[j] = f2bf(bsrc(w, sb, k, col));
  }
  *(short8*)&img[(size_t)d * 8] = v;
}

template <bool PREB>
__global__ void __launch_bounds__(THREADS) kan_main(
    const float* __restrict__ x, const float* __restrict__ rw,
    const float* __restrict__ rc, const float* __restrict__ w,
    const float* __restrict__ bias, const float* __restrict__ sb,
    const short* __restrict__ bimg, float* __restrict__ out) {
  // Double-buffered tiles. A: [BM][BK] bf16 (row = m, 128B, XOR slot^=m&7);
  // B: [BN][BK] bf16 n-major, same swizzle.
  __shared__ __align__(16) short A_lds[2][BM * BK];
  __shared__ __align__(16) short B_lds[2][BN * BK];

  const int t = threadIdx.x;
  const int lane = t & 63;
  const int wid = t >> 6;       // 0..7
  const int wm = wid >> 2;      // 0..1 : 32 rows
  const int wn = wid & 3;       // 0..3 : 32 cols
  const int l15 = lane & 15;
  const int kb = lane >> 4;     // 0..3

  const int m0 = blockIdx.x * BM;
  const int nt = blockIdx.y;
  const int n0 = nt * BN;

  f32x4 acc[2][2];
#pragma unroll
  for (int i = 0; i < 2; ++i)
#pragma unroll
    for (int j = 0; j < 2; ++j) acc[i][j] = (f32x4){0.f, 0.f, 0.f, 0.f};

  // A staging: 512 tasks = (row a_m 0..63) x (feature-octet a_il 0..7)
  const int a_il = t & 7;
  const int a_m = t >> 3;
  // B fallback staging: (n 0..127) x (oct t>>7 and +4)
  const int b_n = t & 127;
  const int b_o = t >> 7;

  const float nbeta = -64.0f / 9.0f;   // -(nb/log2(nb))^2

  // ---- prefetch state (registers) ----
  float xs;                   // phi path x
  float4 rw0, rw1, rc0, rc1;  // phi path params
  float4 xa, xb;              // cos path x
  float bfb[16];              // fallback B f32 staging

  auto issueA = [&](int s) {
    if (s < PHI_STEPS) {
      const int feat = s * 8 + a_il;
      xs = x[(size_t)(m0 + a_m) * IN_F + feat];
      rw0 = *(const float4*)(rw + feat * 8);
      rw1 = *(const float4*)(rw + feat * 8 + 4);
      rc0 = *(const float4*)(rc + feat * 8);
      rc1 = *(const float4*)(rc + feat * 8 + 4);
    } else {
      const float* xp = x + (size_t)(m0 + a_m) * IN_F + (s - PHI_STEPS) * 64 + a_il * 8;
      xa = *(const float4*)xp;
      xb = *(const float4*)(xp + 4);
    }
  };

  auto writeA = [&](int s, int buf) {
    short8 av;
    if (s < PHI_STEPS) {
      const float rwv[8] = {rw0.x, rw0.y, rw0.z, rw0.w, rw1.x, rw1.y, rw1.z, rw1.w};
      const float rcv[8] = {rc0.x, rc0.y, rc0.z, rc0.w, rc1.x, rc1.y, rc1.z, rc1.w};
#pragma unroll
      for (int b = 0; b < 8; ++b) {
        const float z = fmaf(xs, rwv[b], -rcv[b]);
        av[b] = f2bf(__expf(nbeta * z * z));
      }
    } else {
      av[0] = f2bf(__cosf(xa.x)); av[1] = f2bf(__cosf(xa.y));
      av[2] = f2bf(__cosf(xa.z)); av[3] = f2bf(__cosf(xa.w));
      av[4] = f2bf(__cosf(xb.x)); av[5] = f2bf(__cosf(xb.y));
      av[6] = f2bf(__cosf(xb.z)); av[7] = f2bf(__cosf(xb.w));
    }
    const int slot = a_il ^ (a_m & 7);
    *(short8*)&A_lds[buf][a_m * BK + slot * 8] = av;
  };

  auto issueB = [&](int s, int buf) {
    if (PREB) {
      const short* src = bimg + (size_t)(nt * NSTEPS + s) * IMG_SHORTS + t * 8;
      glds16(src, &B_lds[buf][wid * 512]);
      glds16(src + 4096, &B_lds[buf][4096 + wid * 512]);
    } else {
      const float* Bs = (s < PHI_STEPS) ? (w + (size_t)s * 64 * OUT_F)
                                        : (sb + (size_t)(s - PHI_STEPS) * 64 * OUT_F);
      const float* p0 = Bs + (b_o * 8) * OUT_F + n0 + b_n;
      const float* p1 = Bs + ((b_o + 4) * 8) * OUT_F + n0 + b_n;
#pragma unroll
      for (int j = 0; j < 8; ++j) {
        bfb[j] = p0[j * OUT_F];
        bfb[8 + j] = p1[j * OUT_F];
      }
    }
  };

  auto writeB = [&](int buf) {
    if (!PREB) {
      short8 v0, v1;
#pragma unroll
      for (int j = 0; j < 8; ++j) { v0[j] = f2bf(bfb[j]); v1[j] = f2bf(bfb[8 + j]); }
      *(short8*)&B_lds[buf][b_n * BK + (b_o ^ (b_n & 7)) * 8] = v0;
      *(short8*)&B_lds[buf][b_n * BK + ((b_o + 4) ^ (b_n & 7)) * 8] = v1;
    }
  };

  auto mfma_step = [&](int buf) {
#pragma unroll
    for (int kkk = 0; kkk < 2; ++kkk) {
      short8 af[2], bv[2];
#pragma unroll
      for (int mi = 0; mi < 2; ++mi) {
        const int row = wm * 32 + mi * 16 + l15;
        const int slot = (kkk * 4 + kb) ^ (row & 7);
        af[mi] = *(const short8*)&A_lds[buf][row * BK + slot * 8];
      }
#pragma unroll
      for (int ni = 0; ni < 2; ++ni) {
        const int n = wn * 32 + ni * 16 + l15;
        const int slot = (kkk * 4 + kb) ^ (n & 7);
        bv[ni] = *(const short8*)&B_lds[buf][n * BK + slot * 8];
      }
#pragma unroll
      for (int mi = 0; mi < 2; ++mi)
#pragma unroll
        for (int ni = 0; ni < 2; ++ni)
          acc[mi][ni] = __builtin_amdgcn_mfma_f32_16x16x32_bf16(
              af[mi], bv[ni], acc[mi][ni], 0, 0, 0);
    }
  };

  // ---- prologue: stage step 0 into buffer 0 ----
  issueA(0);
  issueB(0, 0);
  writeA(0, 0);
  writeB(0);
  __syncthreads();

  // ---- pipelined main loop: one barrier per K-step ----
  for (int s = 0; s < NSTEPS; ++s) {
    const int c = s & 1;
    if (s + 1 < NSTEPS) {
      issueA(s + 1);          // global loads for next step (latency hidden)
      issueB(s + 1, c ^ 1);   // glds / reg loads into the other buffer
    }
    mfma_step(c);             // compute current step
    if (s + 1 < NSTEPS) {
      writeA(s + 1, c ^ 1);   // exp/cos + ds_write next A tile
      writeB(c ^ 1);
    }
    __syncthreads();          // drain (loads are a full iteration old) + swap
  }

  // ---- epilogue: bias + store ----
#pragma unroll
  for (int ni = 0; ni < 2; ++ni) {
    const int col = n0 + wn * 32 + ni * 16 + l15;
    const float bvv = bias[col];
#pragma unroll
    for (int mi = 0; mi < 2; ++mi) {
      const int rowb = m0 + wm * 32 + mi * 16 + kb * 4;
#pragma unroll
      for (int r = 0; r < 4; ++r)
        out[(size_t)(rowb + r) * OUT_F + col] = acc[mi][ni][r] + bvv;
    }
  }
}

extern "C" void kernel_launch(void* const* d_in, const int* in_sizes, int n_in,
                              void* d_out, int out_size, void* d_ws, size_t ws_size,
                              hipStream_t stream) {
  const float* x    = (const float*)d_in[0];
  const float* rw   = (const float*)d_in[1];
  const float* rc   = (const float*)d_in[2];
  const float* w    = (const float*)d_in[3];
  const float* bias = (const float*)d_in[4];
  const float* sb   = (const float*)d_in[5];
  float* out = (float*)d_out;

  const int nrows = in_sizes[0] / IN_F;        // 8192
  dim3 grid(nrows / BM, NT);                   // (128, 4) = 512 blocks

  const size_t need = (size_t)NT * NSTEPS * IMG_SHORTS * sizeof(short);  // 4.5 MB
  if (ws_size >= need) {
    short* img = (short*)d_ws;
    prep_b<<<NT * NSTEPS * 1024 / 512, 512, 0, stream>>>(w, sb, img);
    kan_main<true><<<grid, THREADS, 0, stream>>>(x, rw, rc, w, bias, sb, img, out);
  } else {
    kan_main<false><<<grid, THREADS, 0, stream>>>(x, rw, rc, w, bias, sb, nullptr, out);
  }
}